// Round 2
// baseline (741.871 us; speedup 1.0000x reference)
//
#include <hip/hip_runtime.h>
#include <math.h>

#define N_ 2048
#define M_ 2048
#define D_ 1024
#define BHW 54            // band half-width: p underflows to exact f64 zero for |i-j| >= 55
#define BW 109            // 2*BHW+1
#define WPAD 112
#define HALO 64
#define NBUF (N_ + 2*HALO)

// ---------------- column stats: c = mean / sqrt(var_ddof1 + 1e-4) ----------------
__global__ void stats_kernel(const float* __restrict__ X, const float* __restrict__ Y,
                             float* __restrict__ cX, float* __restrict__ cY) {
  bool isY = blockIdx.x >= 16;
  const float* src = isY ? Y : X;
  float* c = isY ? cY : cX;
  int cb = (blockIdx.x & 15) * 64;
  int cl = threadIdx.x & 63;
  int rl = threadIdx.x >> 6;       // 4 row-lanes
  int col = cb + cl;
  double sum = 0.0, sq = 0.0;
  for (int r = rl; r < N_; r += 4) {
    float v = src[(size_t)r * D_ + col];
    sum += (double)v;
    sq  += (double)v * (double)v;
  }
  __shared__ double ssum[4][64];
  __shared__ double ssq[4][64];
  ssum[rl][cl] = sum; ssq[rl][cl] = sq;
  __syncthreads();
  if (rl == 0) {
    double S = (ssum[0][cl] + ssum[1][cl]) + (ssum[2][cl] + ssum[3][cl]);
    double Q = (ssq[0][cl]  + ssq[1][cl])  + (ssq[2][cl]  + ssq[3][cl]);
    double mean = S / (double)N_;
    double var  = (Q - S * S / (double)N_) / (double)(N_ - 1);
    c[col] = (float)(mean / sqrt(var + 1e-4));
  }
}

// ---------------- normalize rows + row sum-of-squares ----------------
__global__ void norm_kernel(const float* __restrict__ X, const float* __restrict__ Y,
                            const float* __restrict__ cX, const float* __restrict__ cY,
                            float* __restrict__ Xn, float* __restrict__ Yn,
                            float* __restrict__ xsq, float* __restrict__ ysq) {
  int b = blockIdx.x;
  bool isY = b >= N_;
  int i = isY ? b - N_ : b;
  const float* src = isY ? Y : X;
  const float* c   = isY ? cY : cX;
  float* dst = isY ? Yn : Xn;
  float* rs  = isY ? ysq : xsq;
  int tid = threadIdx.x;                     // 256
  const float4 x  = reinterpret_cast<const float4*>(src + (size_t)i * D_)[tid];
  const float4 cc = reinterpret_cast<const float4*>(c)[tid];
  float4 o = make_float4(x.x - cc.x, x.y - cc.y, x.z - cc.z, x.w - cc.w);
  reinterpret_cast<float4*>(dst + (size_t)i * D_)[tid] = o;
  float ss = o.x*o.x + o.y*o.y + o.z*o.z + o.w*o.w;
  for (int off = 32; off; off >>= 1) ss += __shfl_xor(ss, off);
  __shared__ float wsum[4];
  if ((tid & 63) == 0) wsum[tid >> 6] = ss;
  __syncthreads();
  if (tid == 0) rs[i] = (wsum[0] + wsum[1]) + (wsum[2] + wsum[3]);
}

// ---------------- build banded k (f64), k^T band, and banded d (f32) ----------------
__global__ void band_kernel(const float* __restrict__ Xn, const float* __restrict__ Yn,
                            const float* __restrict__ xsq, const float* __restrict__ ysq,
                            double* __restrict__ kband, double* __restrict__ ktband,
                            float* __restrict__ dband) {
  int i = blockIdx.x;
  int tid = threadIdx.x;                 // 256
  int lane = tid & 63, wv = tid >> 6;
  __shared__ float Xs[D_];
  reinterpret_cast<float4*>(Xs)[tid] = reinterpret_cast<const float4*>(Xn + (size_t)i * D_)[tid];
  // zero the k^T slots of row j=i whose source i is out of range (nobody else writes them)
  for (int dp = tid; dp < BW; dp += 256) {
    int isrc = i - BHW + dp;
    if (isrc < 0 || isrc >= N_) ktband[(size_t)i * WPAD + dp] = 0.0;
  }
  __syncthreads();
  float4 xf[4];
  #pragma unroll
  for (int q = 0; q < 4; ++q) xf[q] = reinterpret_cast<const float4*>(Xs)[q * 64 + lane];
  float xsqi = xsq[i];
  for (int dd = wv; dd < BW; dd += 4) {
    int j = i - BHW + dd;
    if (j < 0 || j >= M_) {
      if (lane == 0) { kband[(size_t)i*WPAD+dd] = 0.0; dband[(size_t)i*WPAD+dd] = 0.0f; }
      continue;
    }
    const float4* yr = reinterpret_cast<const float4*>(Yn + (size_t)j * D_);
    float acc = 0.0f;
    #pragma unroll
    for (int q = 0; q < 4; ++q) {
      float4 y = yr[q * 64 + lane];      // coalesced: lane-contiguous 16B
      acc = fmaf(xf[q].x, y.x, acc);
      acc = fmaf(xf[q].y, y.y, acc);
      acc = fmaf(xf[q].z, y.z, acc);
      acc = fmaf(xf[q].w, y.w, acc);
    }
    for (int off = 32; off; off >>= 1) acc += __shfl_xor(acc, off);
    if (lane == 0) {
      float dv = xsqi + ysq[j] - 2.0f * acc;                 // f32, like reference
      double diff = (double)(i - j) / 2048.0;                // == (i+1)/n - (j+1)/m exactly
      double mid  = sqrt(1.0/((double)N_*(double)N_) + 1.0/((double)M_*(double)M_));
      double dpos = fabs(diff) / mid;
      double p = exp(-(dpos * dpos) / 2.0) / 2.5066282746310002;  // / (DELTA*sqrt(2*pi))
      double s = 50.0 / (diff * diff + 1.0);
      double kk = p * exp((s - (double)dv) / 0.1);
      kband[(size_t)i * WPAD + dd] = kk;
      dband[(size_t)i * WPAD + dd] = dv;
      ktband[(size_t)j * WPAD + (2 * BHW - dd)] = kk;
    }
  }
}

// ---------------- init ----------------
__global__ void init_kernel(double* __restrict__ ua, double* __restrict__ ub,
                            double* __restrict__ vb, double* __restrict__ critacc,
                            double* __restrict__ disacc, int* __restrict__ flag) {
  int tid = threadIdx.x;
  for (int q = tid; q < NBUF; q += 256) {
    int idx = q - HALO;
    ua[q] = (idx >= 0 && idx < N_) ? (1.0 / (double)N_) : 0.0;
    ub[q] = 0.0;
    vb[q] = 0.0;
  }
  if (tid == 0) { *critacc = 0.0; *disacc = 0.0; *flag = 0; }
}

// ---------------- one fused Sinkhorn update: u_out = 1/(n*K*(b/(K^T u_in))) ----------------
// Each block (64 threads) owns 64 rows; recomputes the K^T matvec for a +/-BHW halo of
// columns locally so one kernel = one full iteration (no intermediate sync).
// Guarded kernels become no-ops once converged; consumers select the u buffer via flag.
__global__ void upd_kernel(const double* __restrict__ kband, const double* __restrict__ ktband,
                           const double* __restrict__ uin, double* __restrict__ uout,
                           double* __restrict__ vout, const int* __restrict__ flag, int guarded) {
  if (guarded && *flag) return;
  int tid = threadIdx.x;                 // 64
  int i0 = blockIdx.x * 64;
  __shared__ double wsh[64 + 2 * BHW];
  for (int q = tid; q < 64 + 2 * BHW; q += 64) {
    int j = i0 - BHW + q;
    double v = 0.0;
    if (j >= 0 && j < M_) {
      const double* kr = ktband + (size_t)j * WPAD;
      const double* u  = uin + HALO + j - BHW;
      double w = 0.0;
      for (int d = 0; d < BW; ++d) w += kr[d] * u[d];
      v = (1.0 / (double)M_) / w;        // b / (K^T u)
    }
    wsh[q] = v;
  }
  __syncthreads();
  int i = i0 + tid;
  const double* kr = kband + (size_t)i * WPAD;
  double acc = 0.0;
  for (int d = 0; d < BW; ++d) acc += kr[d] * wsh[tid + d];
  uout[HALO + i] = 1.0 / ((double)N_ * acc);   // 1/(ainvK @ v), ainvK=k*n (exact 2^11 scale)
  if (vout) vout[HALO + i] = wsh[tid + BHW];
}

// ---------------- convergence criterion: crit = sum |v * (K^T u) - b| ----------------
__global__ void crit_kernel(const double* __restrict__ ktband, const double* __restrict__ ub,
                            const double* __restrict__ vb, double* __restrict__ critacc) {
  int j = blockIdx.x * 64 + threadIdx.x;
  const double* kr = ktband + (size_t)j * WPAD;
  const double* u  = ub + HALO + j - BHW;
  double w = 0.0;
  for (int d = 0; d < BW; ++d) w += kr[d] * u[d];
  double val = fabs(vb[HALO + j] * w - (1.0 / (double)M_));
  for (int off = 32; off; off >>= 1) val += __shfl_xor(val, off);
  if (threadIdx.x == 0) atomicAdd(critacc, val);
}

__global__ void flag_kernel(const double* __restrict__ critacc, int* __restrict__ flag) {
  double c = *critacc;
  *flag = (c < 0.005 || isnan(c)) ? 1 : 0;
}

// ---------------- dis = sum(u * ((k*d) @ v)); u buffer selected by flag ----------------
__global__ void dis_kernel(const double* __restrict__ kband, const float* __restrict__ dband,
                           const double* __restrict__ uearly, const double* __restrict__ ulate,
                           const double* __restrict__ vb, const int* __restrict__ flag,
                           double* __restrict__ disacc) {
  const double* ub = *flag ? uearly : ulate;
  int i = blockIdx.x * 64 + threadIdx.x;
  const double* kr = kband + (size_t)i * WPAD;
  const float*  dr = dband + (size_t)i * WPAD;
  const double* v  = vb + HALO + i - BHW;
  double acc = 0.0;
  for (int d = 0; d < BW; ++d) acc += kr[d] * (double)dr[d] * v[d];
  acc *= ub[HALO + i];
  for (int off = 32; off; off >>= 1) acc += __shfl_xor(acc, off);
  if (threadIdx.x == 0) atomicAdd(disacc, acc);
}

// ---------------- t = v^T * (u * k)  (zero outside band) + dis scalar ----------------
__global__ void t_kernel(const double* __restrict__ kband,
                         const double* __restrict__ uearly, const double* __restrict__ ulate,
                         const double* __restrict__ vb, const int* __restrict__ flag,
                         const double* __restrict__ disacc, float* __restrict__ out) {
  const double* ub = *flag ? uearly : ulate;
  int i = blockIdx.x;
  if (i == 0 && threadIdx.x == 0) out[0] = (float)(*disacc);
  double ui = ub[HALO + i];
  float* row = out + 1 + (size_t)i * M_;
  const double* kr = kband + (size_t)i * WPAD;
  for (int j = threadIdx.x; j < M_; j += 256) {
    int dd = j - i + BHW;
    float t = 0.0f;
    if (dd >= 0 && dd < BW) t = (float)(ui * kr[dd] * vb[HALO + j]);
    row[j] = t;
  }
}

extern "C" void kernel_launch(void* const* d_in, const int* in_sizes, int n_in,
                              void* d_out, int out_size, void* d_ws, size_t ws_size,
                              hipStream_t stream) {
  const float* X = (const float*)d_in[0];
  const float* Y = (const float*)d_in[1];
  float* out = (float*)d_out;

  char* p = (char*)d_ws;
  auto alloc = [&](size_t bytes) -> char* {
    char* r = p; p += (bytes + 255) & ~(size_t)255; return r;
  };
  float*  Xn     = (float*) alloc(sizeof(float)  * (size_t)N_ * D_);
  float*  Yn     = (float*) alloc(sizeof(float)  * (size_t)M_ * D_);
  float*  cX     = (float*) alloc(sizeof(float)  * D_);
  float*  cY     = (float*) alloc(sizeof(float)  * D_);
  float*  xsq    = (float*) alloc(sizeof(float)  * N_);
  float*  ysq    = (float*) alloc(sizeof(float)  * M_);
  float*  dband  = (float*) alloc(sizeof(float)  * (size_t)N_ * WPAD);
  double* kband  = (double*)alloc(sizeof(double) * (size_t)N_ * WPAD);
  double* ktband = (double*)alloc(sizeof(double) * (size_t)M_ * WPAD);
  double* ua     = (double*)alloc(sizeof(double) * NBUF);
  double* ub     = (double*)alloc(sizeof(double) * NBUF);
  double* vb     = (double*)alloc(sizeof(double) * NBUF);
  double* critacc= (double*)alloc(256);
  double* disacc = (double*)alloc(256);
  int*    flag   = (int*)   alloc(256);

  stats_kernel<<<32, 256, 0, stream>>>(X, Y, cX, cY);
  norm_kernel<<<2 * N_, 256, 0, stream>>>(X, Y, cX, cY, Xn, Yn, xsq, ysq);
  band_kernel<<<N_, 256, 0, stream>>>(Xn, Yn, xsq, ysq, kband, ktband, dband);
  init_kernel<<<1, 256, 0, stream>>>(ua, ub, vb, critacc, disacc, flag);

  // pass 1: plain update, then special block (v = b/(K^T u); u = 1/(ainvK v))
  upd_kernel<<<32, 64, 0, stream>>>(kband, ktband, ua, ub, nullptr, flag, 0);
  upd_kernel<<<32, 64, 0, stream>>>(kband, ktband, ub, ua, vb, flag, 0);
  // criterion on (u=ua, v=vb)
  crit_kernel<<<32, 64, 0, stream>>>(ktband, ua, vb, critacc);
  flag_kernel<<<1, 1, 0, stream>>>(critacc, flag);

  // 18 plain updates (guarded no-ops if converged), ping-pong ua<->ub
  double* s = ua; double* d = ub;
  for (int t = 0; t < 18; ++t) {
    upd_kernel<<<32, 64, 0, stream>>>(kband, ktband, s, d, nullptr, flag, 1);
    double* tmp = s; s = d; d = tmp;
  }
  // final special block (guarded): v = b/(K^T u); u = 1/(ainvK v);  ua -> ub
  upd_kernel<<<32, 64, 0, stream>>>(kband, ktband, s, d, vb, flag, 1);

  // consumers: if converged early, u lives in ua (pass-1 result); else in ub
  dis_kernel<<<32, 64, 0, stream>>>(kband, dband, ua, d, vb, flag, disacc);
  t_kernel<<<N_, 256, 0, stream>>>(kband, ua, d, vb, flag, disacc, out);
}

// Round 3
// 588.175 us; speedup vs baseline: 1.2613x; 1.2613x over previous
//
#include <hip/hip_runtime.h>
#include <math.h>

#define N_ 2048
#define M_ 2048
#define D_ 1024
#define BHW 54            // band half-width: p underflows to exact f64 zero for |i-j| >= 55
#define BW 109            // 2*BHW+1
#define WPAD 112
#define NB 32             // persistent-kernel blocks
#define ROWS 64           // rows per block in sink kernel
#define VW 172            // ROWS + 2*BHW : v-halo width per block
#define UHALO 128
#define UN (N_ + 2*UHALO)
#define SB 64             // stats partial blocks per matrix

// ---------------- stats phase A: per-block column partial sums ----------------
__global__ void stats_part(const float* __restrict__ X, const float* __restrict__ Y,
                           double* __restrict__ psum, double* __restrict__ psq,
                           int* __restrict__ cnt, int* __restrict__ gen) {
  if (blockIdx.x == 0 && threadIdx.x == 0) { *cnt = 0; *gen = 0; }  // barrier vars for sink
  int b = blockIdx.x;                  // 0..127
  bool isY = b >= SB;
  const float* src = isY ? Y : X;
  int pb = isY ? b - SB : b;
  int tid = threadIdx.x;               // 256 -> float4 column group
  int r0 = pb * (N_ / SB);             // 32 rows per block
  double s0=0,s1=0,s2=0,s3=0,q0=0,q1=0,q2=0,q3=0;
  for (int r = 0; r < N_ / SB; ++r) {
    float4 v = reinterpret_cast<const float4*>(src + (size_t)(r0 + r) * D_)[tid];
    s0 += v.x; q0 += (double)v.x * v.x;
    s1 += v.y; q1 += (double)v.y * v.y;
    s2 += v.z; q2 += (double)v.z * v.z;
    s3 += v.w; q3 += (double)v.w * v.w;
  }
  double* ps = psum + (size_t)b * D_ + 4 * tid;
  double* pq = psq  + (size_t)b * D_ + 4 * tid;
  ps[0]=s0; ps[1]=s1; ps[2]=s2; ps[3]=s3;
  pq[0]=q0; pq[1]=q1; pq[2]=q2; pq[3]=q3;
}

// ---------------- stats phase B: reduce partials -> c = mean/sqrt(var+eps) ----------------
__global__ void stats_red(const double* __restrict__ psum, const double* __restrict__ psq,
                          float* __restrict__ cX, float* __restrict__ cY) {
  int g = blockIdx.x * 64 + threadIdx.x;   // 2048 threads: matrix = g>>10, col = g&1023
  int m = g >> 10, col = g & 1023;
  const double* ps = psum + (size_t)m * SB * D_ + col;
  const double* pq = psq  + (size_t)m * SB * D_ + col;
  double S = 0.0, Q = 0.0;
  for (int p2 = 0; p2 < SB; ++p2) { S += ps[(size_t)p2 * D_]; Q += pq[(size_t)p2 * D_]; }
  double mean = S / (double)N_;
  double var  = (Q - S * S / (double)N_) / (double)(N_ - 1);
  (m ? cY : cX)[col] = (float)(mean / sqrt(var + 1e-4));
}

// ---------------- normalize rows + row sum-of-squares ----------------
__global__ void norm_kernel(const float* __restrict__ X, const float* __restrict__ Y,
                            const float* __restrict__ cX, const float* __restrict__ cY,
                            float* __restrict__ Xn, float* __restrict__ Yn,
                            float* __restrict__ xsq, float* __restrict__ ysq) {
  int b = blockIdx.x;
  bool isY = b >= N_;
  int i = isY ? b - N_ : b;
  const float* src = isY ? Y : X;
  const float* c   = isY ? cY : cX;
  float* dst = isY ? Yn : Xn;
  float* rs  = isY ? ysq : xsq;
  int tid = threadIdx.x;                     // 256
  const float4 x  = reinterpret_cast<const float4*>(src + (size_t)i * D_)[tid];
  const float4 cc = reinterpret_cast<const float4*>(c)[tid];
  float4 o = make_float4(x.x - cc.x, x.y - cc.y, x.z - cc.z, x.w - cc.w);
  reinterpret_cast<float4*>(dst + (size_t)i * D_)[tid] = o;
  float ss = o.x*o.x + o.y*o.y + o.z*o.z + o.w*o.w;
  for (int off = 32; off; off >>= 1) ss += __shfl_xor(ss, off);
  __shared__ float wsum[4];
  if ((tid & 63) == 0) wsum[tid >> 6] = ss;
  __syncthreads();
  if (tid == 0) rs[i] = (wsum[0] + wsum[1]) + (wsum[2] + wsum[3]);
}

// ---------------- build banded k (f64), k^T band, and banded d (f32) ----------------
__global__ void band_kernel(const float* __restrict__ Xn, const float* __restrict__ Yn,
                            const float* __restrict__ xsq, const float* __restrict__ ysq,
                            double* __restrict__ kband, double* __restrict__ ktband,
                            float* __restrict__ dband) {
  int i = blockIdx.x;
  int tid = threadIdx.x;                 // 256
  int lane = tid & 63, wv = tid >> 6;
  __shared__ float Xs[D_];
  reinterpret_cast<float4*>(Xs)[tid] = reinterpret_cast<const float4*>(Xn + (size_t)i * D_)[tid];
  for (int dp = tid; dp < BW; dp += 256) {
    int isrc = i - BHW + dp;
    if (isrc < 0 || isrc >= N_) ktband[(size_t)i * WPAD + dp] = 0.0;
  }
  __syncthreads();
  float4 xf[4];
  #pragma unroll
  for (int q = 0; q < 4; ++q) xf[q] = reinterpret_cast<const float4*>(Xs)[q * 64 + lane];
  float xsqi = xsq[i];
  for (int dd = wv; dd < BW; dd += 4) {
    int j = i - BHW + dd;
    if (j < 0 || j >= M_) {
      if (lane == 0) { kband[(size_t)i*WPAD+dd] = 0.0; dband[(size_t)i*WPAD+dd] = 0.0f; }
      continue;
    }
    const float4* yr = reinterpret_cast<const float4*>(Yn + (size_t)j * D_);
    float acc = 0.0f;
    #pragma unroll
    for (int q = 0; q < 4; ++q) {
      float4 y = yr[q * 64 + lane];
      acc = fmaf(xf[q].x, y.x, acc);
      acc = fmaf(xf[q].y, y.y, acc);
      acc = fmaf(xf[q].z, y.z, acc);
      acc = fmaf(xf[q].w, y.w, acc);
    }
    for (int off = 32; off; off >>= 1) acc += __shfl_xor(acc, off);
    if (lane == 0) {
      float dv = xsqi + ysq[j] - 2.0f * acc;
      double diff = (double)(i - j) / 2048.0;
      double mid  = sqrt(1.0/((double)N_*(double)N_) + 1.0/((double)M_*(double)M_));
      double dpos = fabs(diff) / mid;
      double p = exp(-(dpos * dpos) / 2.0) / 2.5066282746310002;
      double s = 50.0 / (diff * diff + 1.0);
      double kk = p * exp((s - (double)dv) / 0.1);
      kband[(size_t)i * WPAD + dd] = kk;
      dband[(size_t)i * WPAD + dd] = dv;
      ktband[(size_t)j * WPAD + (2 * BHW - dd)] = kk;
    }
  }
}

// ---------------- device-scope sense-reversing grid barrier ----------------
__device__ __forceinline__ void gbar(int* cnt, int* gen) {
  __syncthreads();
  if (threadIdx.x == 0) {
    __threadfence();
    int g = __hip_atomic_load(gen, __ATOMIC_ACQUIRE, __HIP_MEMORY_SCOPE_AGENT);
    if (__hip_atomic_fetch_add(cnt, 1, __ATOMIC_ACQ_REL, __HIP_MEMORY_SCOPE_AGENT) == NB - 1) {
      __hip_atomic_store(cnt, 0, __ATOMIC_RELAXED, __HIP_MEMORY_SCOPE_AGENT);
      __hip_atomic_fetch_add(gen, 1, __ATOMIC_ACQ_REL, __HIP_MEMORY_SCOPE_AGENT);  // release: cnt reset ordered before
    } else {
      while (__hip_atomic_load(gen, __ATOMIC_ACQUIRE, __HIP_MEMORY_SCOPE_AGENT) == g)
        __builtin_amdgcn_s_sleep(2);
    }
  }
  __syncthreads();
}

// ---------------- persistent fused Sinkhorn + crit + dis + t ----------------
// 32 blocks x 256 threads, all co-resident. One grid barrier per iteration:
// each block redundantly computes the 172-wide v-halo it needs, then its own 64 u'.
__global__ void __launch_bounds__(256)
sink_kernel(const double* __restrict__ kband, const double* __restrict__ ktband,
            const float* __restrict__ dband,
            double* __restrict__ uA, double* __restrict__ uB, double* __restrict__ vfin,
            double* __restrict__ critacc, double* __restrict__ disacc,
            int* cnt, int* gen, float* __restrict__ out) {
  int tid = threadIdx.x;
  int i0 = blockIdx.x * ROWS;
  int gtid = blockIdx.x * 256 + tid;
  __shared__ double vsh[VW];
  __shared__ double red[4];

  // init u buffers (incl. zero pads), v pads, accumulators
  for (int q = gtid; q < UN; q += NB * 256) {
    int idx = q - UHALO;
    uA[q] = (idx >= 0 && idx < N_) ? (1.0 / (double)N_) : 0.0;
    uB[q] = 0.0;
    vfin[q] = 0.0;
  }
  if (gtid == 0) { *critacc = 0.0; *disacc = 0.0; }

  double* cur = uA; double* nxt = uB;
  int p = tid & 3, o0 = tid >> 2;
  int d0 = p * 28, dcnt = (p == 3) ? 25 : 28;

  auto seg = [&](int writeV) {
    gbar(cnt, gen);                       // prev u writes (and init) visible
    for (int o = o0; o < VW; o += 64) {   // v for j in [i0-54, i0+117]
      int j = i0 - BHW + o;
      double w = 0.0;
      if (j >= 0 && j < M_) {
        const double* kr = ktband + (size_t)j * WPAD + d0;
        const double* u  = cur + UHALO + j - BHW + d0;
        for (int d2 = 0; d2 < dcnt; ++d2) w += kr[d2] * u[d2];
      }
      w += __shfl_xor(w, 1); w += __shfl_xor(w, 2);
      if (p == 0) vsh[o] = (j >= 0 && j < M_) ? (1.0 / (double)M_) / w : 0.0;
    }
    __syncthreads();
    {
      int i = i0 + o0;
      const double* kr = kband + (size_t)i * WPAD + d0;
      double acc = 0.0;
      for (int d2 = 0; d2 < dcnt; ++d2) acc += kr[d2] * vsh[o0 + d0 + d2];
      acc += __shfl_xor(acc, 1); acc += __shfl_xor(acc, 2);
      if (p == 0) {
        nxt[UHALO + i] = 1.0 / ((double)N_ * acc);   // ainvK = k*n (exact 2^11 scale)
        if (writeV) vfin[UHALO + i] = vsh[o0 + BHW];
      }
    }
    double* t = cur; cur = nxt; nxt = t;
  };

  seg(0);            // u1 (plain update #1)
  seg(1);            // v1 = b/(K^T u1); u2 = 1/(ainvK v1)
  gbar(cnt, gen);    // u2, v1 visible

  // crit = sum |v1 * (K^T u2) - b|
  {
    int j = i0 + o0;
    const double* kr = ktband + (size_t)j * WPAD + d0;
    const double* u  = cur + UHALO + j - BHW + d0;
    double w = 0.0;
    for (int d2 = 0; d2 < dcnt; ++d2) w += kr[d2] * u[d2];
    w += __shfl_xor(w, 1); w += __shfl_xor(w, 2);
    double c = (p == 0) ? fabs(vfin[UHALO + j] * w - 1.0 / (double)M_) : 0.0;
    for (int off = 1; off <= 32; off <<= 1) c += __shfl_xor(c, off);
    if ((tid & 63) == 0) red[tid >> 6] = c;
    __syncthreads();
    if (tid == 0) atomicAdd(critacc, (red[0] + red[1]) + (red[2] + red[3]));
    __syncthreads();
  }
  gbar(cnt, gen);    // critacc complete

  double critv = *critacc;
  bool done = (critv < 0.005) || isnan(critv);   // uniform across grid
  if (!done) {
    for (int it = 0; it < 18; ++it) seg(0);      // 18 plain updates
    seg(1);                                      // final v, u
  }
  gbar(cnt, gen);    // final u/v visible

  // dis = sum(u * ((k .* d) @ v))
  {
    int i = i0 + o0;
    const double* kr = kband + (size_t)i * WPAD + d0;
    const float*  dr = dband + (size_t)i * WPAD + d0;
    const double* vr = vfin + UHALO + i - BHW + d0;
    double acc = 0.0;
    for (int d2 = 0; d2 < dcnt; ++d2) acc += kr[d2] * (double)dr[d2] * vr[d2];
    acc += __shfl_xor(acc, 1); acc += __shfl_xor(acc, 2);
    double c = (p == 0) ? acc * cur[UHALO + i] : 0.0;
    for (int off = 1; off <= 32; off <<= 1) c += __shfl_xor(c, off);
    if ((tid & 63) == 0) red[tid >> 6] = c;
    __syncthreads();
    if (tid == 0) atomicAdd(disacc, (red[0] + red[1]) + (red[2] + red[3]));
    __syncthreads();
  }
  gbar(cnt, gen);    // disacc complete

  // out[0] = dis ; out[1..] = t = v^T * (u .* k), zero outside band
  if (gtid == 0) out[0] = (float)(*disacc);
  for (int idx = gtid; idx < N_ * M_; idx += NB * 256) {
    int i = idx >> 11, j = idx & 2047;
    int dd = j - i + BHW;
    float t = 0.0f;
    if (dd >= 0 && dd < BW)
      t = (float)(cur[UHALO + i] * kband[(size_t)i * WPAD + dd] * vfin[UHALO + j]);
    out[1 + idx] = t;
  }
}

extern "C" void kernel_launch(void* const* d_in, const int* in_sizes, int n_in,
                              void* d_out, int out_size, void* d_ws, size_t ws_size,
                              hipStream_t stream) {
  const float* X = (const float*)d_in[0];
  const float* Y = (const float*)d_in[1];
  float* out = (float*)d_out;

  char* pp = (char*)d_ws;
  auto alloc = [&](size_t bytes) -> char* {
    char* r = pp; pp += (bytes + 255) & ~(size_t)255; return r;
  };
  float*  Xn     = (float*) alloc(sizeof(float)  * (size_t)N_ * D_);
  float*  Yn     = (float*) alloc(sizeof(float)  * (size_t)M_ * D_);
  float*  cX     = (float*) alloc(sizeof(float)  * D_);
  float*  cY     = (float*) alloc(sizeof(float)  * D_);
  float*  xsq    = (float*) alloc(sizeof(float)  * N_);
  float*  ysq    = (float*) alloc(sizeof(float)  * M_);
  float*  dband  = (float*) alloc(sizeof(float)  * (size_t)N_ * WPAD);
  double* kband  = (double*)alloc(sizeof(double) * (size_t)N_ * WPAD);
  double* ktband = (double*)alloc(sizeof(double) * (size_t)M_ * WPAD);
  double* psum   = (double*)alloc(sizeof(double) * (size_t)2 * SB * D_);
  double* psq    = (double*)alloc(sizeof(double) * (size_t)2 * SB * D_);
  double* uA     = (double*)alloc(sizeof(double) * UN);
  double* uB     = (double*)alloc(sizeof(double) * UN);
  double* vfin   = (double*)alloc(sizeof(double) * UN);
  double* critacc= (double*)alloc(256);
  double* disacc = (double*)alloc(256);
  int*    cnt    = (int*)   alloc(256);
  int*    gen    = (int*)   alloc(256);

  stats_part<<<2 * SB, 256, 0, stream>>>(X, Y, psum, psq, cnt, gen);
  stats_red<<<32, 64, 0, stream>>>(psum, psq, cX, cY);
  norm_kernel<<<2 * N_, 256, 0, stream>>>(X, Y, cX, cY, Xn, Yn, xsq, ysq);
  band_kernel<<<N_, 256, 0, stream>>>(Xn, Yn, xsq, ysq, kband, ktband, dband);
  sink_kernel<<<NB, 256, 0, stream>>>(kband, ktband, dband, uA, uB, vfin,
                                      critacc, disacc, cnt, gen, out);
}

// Round 6
// 514.260 us; speedup vs baseline: 1.4426x; 1.1437x over previous
//
#include <hip/hip_runtime.h>
#include <math.h>

#define N_ 2048
#define M_ 2048
#define D_ 1024
#define BHW 54            // band half-width: p underflows to exact f64 zero for |i-j| >= 55
#define BW 109            // 2*BHW+1
#define WPAD 112
#define NB 128            // persistent-kernel blocks (all co-resident on 256 CUs)
#define ROWS 16           // u-rows per block
#define VW 124            // ROWS + 2*BHW : v-halo width per block
#define USHW 232          // VW + 2*BHW  : u-halo needed to build the v-halo
#define UHALO 128
#define UN (N_ + 2*UHALO)
#define SB 64             // stats partial blocks per matrix

// ---------------- stats phase A: per-block column partial sums ----------------
__global__ void stats_part(const float* __restrict__ X, const float* __restrict__ Y,
                           double* __restrict__ psum, double* __restrict__ psq) {
  int b = blockIdx.x;                  // 0..127
  bool isY = b >= SB;
  const float* src = isY ? Y : X;
  int pb = isY ? b - SB : b;
  int tid = threadIdx.x;               // 256 -> float4 column group
  int r0 = pb * (N_ / SB);             // 32 rows per block
  double s0=0,s1=0,s2=0,s3=0,q0=0,q1=0,q2=0,q3=0;
  for (int r = 0; r < N_ / SB; ++r) {
    float4 v = reinterpret_cast<const float4*>(src + (size_t)(r0 + r) * D_)[tid];
    s0 += v.x; q0 += (double)v.x * v.x;
    s1 += v.y; q1 += (double)v.y * v.y;
    s2 += v.z; q2 += (double)v.z * v.z;
    s3 += v.w; q3 += (double)v.w * v.w;
  }
  double* ps = psum + (size_t)b * D_ + 4 * tid;
  double* pq = psq  + (size_t)b * D_ + 4 * tid;
  ps[0]=s0; ps[1]=s1; ps[2]=s2; ps[3]=s3;
  pq[0]=q0; pq[1]=q1; pq[2]=q2; pq[3]=q3;
}

// ---------------- stats phase B: reduce partials -> c = mean/sqrt(var+eps) ----------------
__global__ void stats_red(const double* __restrict__ psum, const double* __restrict__ psq,
                          float* __restrict__ cX, float* __restrict__ cY) {
  int g = blockIdx.x * 64 + threadIdx.x;   // 2048 threads: matrix = g>>10, col = g&1023
  int m = g >> 10, col = g & 1023;
  const double* ps = psum + (size_t)m * SB * D_ + col;
  const double* pq = psq  + (size_t)m * SB * D_ + col;
  double S = 0.0, Q = 0.0;
  for (int p2 = 0; p2 < SB; ++p2) { S += ps[(size_t)p2 * D_]; Q += pq[(size_t)p2 * D_]; }
  double mean = S / (double)N_;
  double var  = (Q - S * S / (double)N_) / (double)(N_ - 1);
  (m ? cY : cX)[col] = (float)(mean / sqrt(var + 1e-4));
}

// ---------------- normalize rows + row sum-of-squares ----------------
__global__ void norm_kernel(const float* __restrict__ X, const float* __restrict__ Y,
                            const float* __restrict__ cX, const float* __restrict__ cY,
                            float* __restrict__ Xn, float* __restrict__ Yn,
                            float* __restrict__ xsq, float* __restrict__ ysq) {
  int b = blockIdx.x;
  bool isY = b >= N_;
  int i = isY ? b - N_ : b;
  const float* src = isY ? Y : X;
  const float* c   = isY ? cY : cX;
  float* dst = isY ? Yn : Xn;
  float* rs  = isY ? ysq : xsq;
  int tid = threadIdx.x;                     // 256
  const float4 x  = reinterpret_cast<const float4*>(src + (size_t)i * D_)[tid];
  const float4 cc = reinterpret_cast<const float4*>(c)[tid];
  float4 o = make_float4(x.x - cc.x, x.y - cc.y, x.z - cc.z, x.w - cc.w);
  reinterpret_cast<float4*>(dst + (size_t)i * D_)[tid] = o;
  float ss = o.x*o.x + o.y*o.y + o.z*o.z + o.w*o.w;
  for (int off = 32; off; off >>= 1) ss += __shfl_xor(ss, off);
  __shared__ float wsum[4];
  if ((tid & 63) == 0) wsum[tid >> 6] = ss;
  __syncthreads();
  if (tid == 0) rs[i] = (wsum[0] + wsum[1]) + (wsum[2] + wsum[3]);
}

// ---------------- build banded k (f64), k^T band, and banded d (f32) ----------------
__global__ void band_kernel(const float* __restrict__ Xn, const float* __restrict__ Yn,
                            const float* __restrict__ xsq, const float* __restrict__ ysq,
                            double* __restrict__ kband, double* __restrict__ ktband,
                            float* __restrict__ dband) {
  int i = blockIdx.x;
  int tid = threadIdx.x;                 // 256
  int lane = tid & 63, wv = tid >> 6;
  __shared__ float Xs[D_];
  reinterpret_cast<float4*>(Xs)[tid] = reinterpret_cast<const float4*>(Xn + (size_t)i * D_)[tid];
  for (int dp = tid; dp < BW; dp += 256) {
    int isrc = i - BHW + dp;
    if (isrc < 0 || isrc >= N_) ktband[(size_t)i * WPAD + dp] = 0.0;
  }
  __syncthreads();
  float4 xf[4];
  #pragma unroll
  for (int q = 0; q < 4; ++q) xf[q] = reinterpret_cast<const float4*>(Xs)[q * 64 + lane];
  float xsqi = xsq[i];
  for (int dd = wv; dd < BW; dd += 4) {
    int j = i - BHW + dd;
    if (j < 0 || j >= M_) {
      if (lane == 0) { kband[(size_t)i*WPAD+dd] = 0.0; dband[(size_t)i*WPAD+dd] = 0.0f; }
      continue;
    }
    const float4* yr = reinterpret_cast<const float4*>(Yn + (size_t)j * D_);
    float acc = 0.0f;
    #pragma unroll
    for (int q = 0; q < 4; ++q) {
      float4 y = yr[q * 64 + lane];
      acc = fmaf(xf[q].x, y.x, acc);
      acc = fmaf(xf[q].y, y.y, acc);
      acc = fmaf(xf[q].z, y.z, acc);
      acc = fmaf(xf[q].w, y.w, acc);
    }
    for (int off = 32; off; off >>= 1) acc += __shfl_xor(acc, off);
    if (lane == 0) {
      float dv = xsqi + ysq[j] - 2.0f * acc;
      double diff = (double)(i - j) / 2048.0;
      double mid  = sqrt(1.0/((double)N_*(double)N_) + 1.0/((double)M_*(double)M_));
      double dpos = fabs(diff) / mid;
      double p = exp(-(dpos * dpos) / 2.0) / 2.5066282746310002;
      double s = 50.0 / (diff * diff + 1.0);
      double kk = p * exp((s - (double)dv) / 0.1);
      kband[(size_t)i * WPAD + dd] = kk;
      dband[(size_t)i * WPAD + dd] = dv;
      ktband[(size_t)j * WPAD + (2 * BHW - dd)] = kk;
    }
  }
}

// ---------------- epoch flag-array grid barrier (garbage-tolerant: poison < ep) --------
__device__ __forceinline__ void gbar(int* flags, int* go, int ep) {
  __syncthreads();
  if (blockIdx.x == 0) {
    int t = threadIdx.x;
    if (t >= 1 && t < NB)
      while (__hip_atomic_load(&flags[t * 16], __ATOMIC_ACQUIRE, __HIP_MEMORY_SCOPE_AGENT) < ep)
        __builtin_amdgcn_s_sleep(1);
    __syncthreads();
    if (t == 0) {
      __threadfence();
      __hip_atomic_store(go, ep, __ATOMIC_RELEASE, __HIP_MEMORY_SCOPE_AGENT);
    }
  } else {
    if (threadIdx.x == 0) {
      __threadfence();
      __hip_atomic_store(&flags[blockIdx.x * 16], ep, __ATOMIC_RELEASE, __HIP_MEMORY_SCOPE_AGENT);
      while (__hip_atomic_load(go, __ATOMIC_ACQUIRE, __HIP_MEMORY_SCOPE_AGENT) < ep)
        __builtin_amdgcn_s_sleep(1);
    }
  }
  __syncthreads();
}

// ---------------- persistent fused Sinkhorn + crit + dis + t ----------------
// 128 blocks x 256 threads. k rows live in REGISTERS (iteration-invariant);
// u halo staged in LDS each seg; one grid barrier per seg.
// crit/dis: each block reduces ONLY its own 16 rows (128*16 = 2048, no overlap).
__global__ void __launch_bounds__(256, 1)
sink_kernel(const double* __restrict__ kband, const double* __restrict__ ktband,
            const float* __restrict__ dband,
            double* __restrict__ uA, double* __restrict__ uB, double* __restrict__ vfin,
            double* __restrict__ critacc, double* __restrict__ disacc,
            int* flags, int* go, float* __restrict__ out) {
  const int tid = threadIdx.x;
  const int i0 = blockIdx.x * ROWS;
  const int gtid = blockIdx.x * 256 + tid;
  const int p = tid & 3, o0 = tid >> 2;     // 64 dot-groups x 4 d-quarter lanes

  __shared__ double ush[240];               // u halo [i0-108, i0+124) + zero pad
  __shared__ double vsh[128];               // v halo [i0-54, i0+70) + zero pad

  // init u buffers (incl. zero pads) and accumulators
  for (int q = gtid; q < UN; q += NB * 256) {
    int idx = q - UHALO;
    uA[q] = (idx >= 0 && idx < N_) ? (1.0 / (double)N_) : 0.0;
    uB[q] = 0.0;
    vfin[q] = 0.0;
  }
  if (gtid == 0) { *critacc = 0.0; *disacc = 0.0; }
  if (tid >= VW && tid < 128) vsh[tid] = 0.0;   // zero vsh pad once (never rewritten)

  // hoist iteration-invariant k rows into registers (static indices -> VGPRs)
  double kv1[28], kv2[28], ku[28];
  {
    int j1 = i0 - BHW + o0;          // v-round-1 row
    bool ok1 = (j1 >= 0 && j1 < M_);
    int j2 = j1 + 64;                // v-round-2 row
    bool ok2 = (o0 < VW - 64) && (j2 < M_);
    int iu = i0 + o0;                // u-phase row (only o0<ROWS used)
    bool oku = (o0 < ROWS);
    #pragma unroll
    for (int d2 = 0; d2 < 28; ++d2) {
      int dd = p * 28 + d2;
      bool din = dd < BW;            // skip the 3 poisoned pad slots
      kv1[d2] = (ok1 && din) ? ktband[(size_t)j1 * WPAD + dd] : 0.0;
      kv2[d2] = (ok2 && din) ? ktband[(size_t)j2 * WPAD + dd] : 0.0;
      ku[d2]  = (oku && din) ? kband[(size_t)iu * WPAD + dd] : 0.0;
    }
  }

  int ep = 0;
  double* cur = uA; double* nxt = uB;

  auto seg = [&](int writeV) {
    ++ep; gbar(flags, go, ep);                 // prev u writes visible
    for (int q = tid; q < 240; q += 256)
      ush[q] = (q < USHW) ? cur[UHALO + i0 - 2 * BHW + q] : 0.0;
    __syncthreads();
    // v-phase round 1: v_j, j = i0-54+o0
    double w = 0.0;
    #pragma unroll
    for (int d2 = 0; d2 < 28; ++d2) w += kv1[d2] * ush[o0 + p * 28 + d2];
    w += __shfl_xor(w, 1); w += __shfl_xor(w, 2);
    if (p == 0) {
      int j = i0 - BHW + o0;
      vsh[o0] = (j >= 0 && j < M_) ? (1.0 / (double)M_) / w : 0.0;
    }
    // v-phase round 2: j = i0-54+o0+64
    double w2 = 0.0;
    #pragma unroll
    for (int d2 = 0; d2 < 28; ++d2) w2 += kv2[d2] * ush[o0 + 64 + p * 28 + d2];
    w2 += __shfl_xor(w2, 1); w2 += __shfl_xor(w2, 2);
    if (p == 0 && o0 < VW - 64) {
      int j = i0 - BHW + o0 + 64;
      vsh[o0 + 64] = (j < M_) ? (1.0 / (double)M_) / w2 : 0.0;
    }
    __syncthreads();
    // u-phase: u_i, i = i0+o0 (o0 < 16)
    if (o0 < ROWS) {
      double acc = 0.0;
      #pragma unroll
      for (int d2 = 0; d2 < 28; ++d2) acc += ku[d2] * vsh[o0 + p * 28 + d2];
      acc += __shfl_xor(acc, 1); acc += __shfl_xor(acc, 2);
      if (p == 0) {
        nxt[UHALO + i0 + o0] = 1.0 / ((double)N_ * acc);  // ainvK = k*n (exact 2^11 scale)
        if (writeV) vfin[UHALO + i0 + o0] = vsh[o0 + BHW];
      }
    }
    double* t = cur; cur = nxt; nxt = t;
  };

  seg(0);            // u1 (plain update #1)
  seg(1);            // v1 = b/(K^T u1); u2 = 1/(ainvK v1)
  ++ep; gbar(flags, go, ep);   // u2, vfin visible

  // crit = sum |v1 * (K^T u2) - b| : this block's 16 rows only
  if (tid < 64) {
    int j = i0 + (tid >> 2);           // 16 rows x 4 quarter-lanes
    const double* kr = ktband + (size_t)j * WPAD + p * 28;
    const double* u  = cur + UHALO + j - BHW + p * 28;
    int dc = (p == 3) ? 25 : 28;
    double w = 0.0;
    for (int d2 = 0; d2 < dc; ++d2) w += kr[d2] * u[d2];
    w += __shfl_xor(w, 1); w += __shfl_xor(w, 2);
    double c = (p == 0) ? fabs(vfin[UHALO + j] * w - 1.0 / (double)M_) : 0.0;
    for (int off = 4; off <= 32; off <<= 1) c += __shfl_xor(c, off);
    if (tid == 0) atomicAdd(critacc, c);
  }
  ++ep; gbar(flags, go, ep);   // critacc complete

  double cv = *critacc;
  bool done = (cv < 0.005) || isnan(cv);   // uniform across grid
  if (!done) {
    for (int it = 0; it < 18; ++it) seg(0);
    seg(1);
  }
  ++ep; gbar(flags, go, ep);   // final u/v visible

  // dis = sum(u * ((k .* d) @ v)) : this block's 16 rows only
  if (tid < 64) {
    int i = i0 + (tid >> 2);
    const double* kr = kband + (size_t)i * WPAD + p * 28;
    const float*  dr = dband + (size_t)i * WPAD + p * 28;
    const double* vr = vfin + UHALO + i - BHW + p * 28;
    int dc = (p == 3) ? 25 : 28;
    double acc = 0.0;
    for (int d2 = 0; d2 < dc; ++d2) acc += kr[d2] * (double)dr[d2] * vr[d2];
    acc += __shfl_xor(acc, 1); acc += __shfl_xor(acc, 2);
    double c = (p == 0) ? acc * cur[UHALO + i] : 0.0;
    for (int off = 4; off <= 32; off <<= 1) c += __shfl_xor(c, off);
    if (tid == 0) atomicAdd(disacc, c);
  }
  ++ep; gbar(flags, go, ep);   // disacc complete

  // out[0] = dis ; out[1..] = t = v^T * (u .* k), zero outside band
  if (gtid == 0) out[0] = (float)(*disacc);
  for (int idx = gtid; idx < N_ * M_; idx += NB * 256) {
    int i = idx >> 11, j = idx & 2047;
    int dd = j - i + BHW;
    float tv = 0.0f;
    if (dd >= 0 && dd < BW)
      tv = (float)(cur[UHALO + i] * kband[(size_t)i * WPAD + dd] * vfin[UHALO + j]);
    out[1 + idx] = tv;
  }
}

extern "C" void kernel_launch(void* const* d_in, const int* in_sizes, int n_in,
                              void* d_out, int out_size, void* d_ws, size_t ws_size,
                              hipStream_t stream) {
  const float* X = (const float*)d_in[0];
  const float* Y = (const float*)d_in[1];
  float* out = (float*)d_out;

  char* pp = (char*)d_ws;
  auto alloc = [&](size_t bytes) -> char* {
    char* r = pp; pp += (bytes + 255) & ~(size_t)255; return r;
  };
  float*  Xn     = (float*) alloc(sizeof(float)  * (size_t)N_ * D_);
  float*  Yn     = (float*) alloc(sizeof(float)  * (size_t)M_ * D_);
  float*  cX     = (float*) alloc(sizeof(float)  * D_);
  float*  cY     = (float*) alloc(sizeof(float)  * D_);
  float*  xsq    = (float*) alloc(sizeof(float)  * N_);
  float*  ysq    = (float*) alloc(sizeof(float)  * M_);
  float*  dband  = (float*) alloc(sizeof(float)  * (size_t)N_ * WPAD);
  double* kband  = (double*)alloc(sizeof(double) * (size_t)N_ * WPAD);
  double* ktband = (double*)alloc(sizeof(double) * (size_t)M_ * WPAD);
  double* psum   = (double*)alloc(sizeof(double) * (size_t)2 * SB * D_);
  double* psq    = (double*)alloc(sizeof(double) * (size_t)2 * SB * D_);
  double* uA     = (double*)alloc(sizeof(double) * UN);
  double* uB     = (double*)alloc(sizeof(double) * UN);
  double* vfin   = (double*)alloc(sizeof(double) * UN);
  double* critacc= (double*)alloc(256);
  double* disacc = (double*)alloc(256);
  int*    flags  = (int*)   alloc(sizeof(int) * NB * 16);
  int*    go     = (int*)   alloc(256);

  stats_part<<<2 * SB, 256, 0, stream>>>(X, Y, psum, psq);
  stats_red<<<32, 64, 0, stream>>>(psum, psq, cX, cY);
  norm_kernel<<<2 * N_, 256, 0, stream>>>(X, Y, cX, cY, Xn, Yn, xsq, ysq);
  band_kernel<<<N_, 256, 0, stream>>>(Xn, Yn, xsq, ysq, kband, ktband, dband);
  sink_kernel<<<NB, 256, 0, stream>>>(kband, ktband, dband, uA, uB, vfin,
                                      critacc, disacc, flags, go, out);
}

// Round 10
// 341.934 us; speedup vs baseline: 2.1696x; 1.5040x over previous
//
#include <hip/hip_runtime.h>
#include <math.h>

#define N_ 2048
#define M_ 2048
#define D_ 1024
#define BHW 54            // band half-width: p underflows to exact f64 zero for |i-j| >= 55
#define BW 109            // 2*BHW+1
#define WPAD 112
#define NB 128            // persistent-kernel blocks (all co-resident on 256 CUs)
#define ROWS 16           // u-rows per block
#define VW 124            // ROWS + 2*BHW : v-halo width per block
#define USHW 232          // VW + 2*BHW  : u-halo needed to build the v-halo
#define UHALO 128
#define UN (N_ + 2*UHALO)
#define SB 64             // stats partial blocks per matrix

// ---------------- stats phase A: per-block column partial sums ----------------
__global__ void stats_part(const float* __restrict__ X, const float* __restrict__ Y,
                           double* __restrict__ psum, double* __restrict__ psq) {
  int b = blockIdx.x;                  // 0..127
  bool isY = b >= SB;
  const float* src = isY ? Y : X;
  int pb = isY ? b - SB : b;
  int tid = threadIdx.x;               // 256 -> float4 column group
  int r0 = pb * (N_ / SB);             // 32 rows per block
  double s0=0,s1=0,s2=0,s3=0,q0=0,q1=0,q2=0,q3=0;
  for (int r = 0; r < N_ / SB; ++r) {
    float4 v = reinterpret_cast<const float4*>(src + (size_t)(r0 + r) * D_)[tid];
    s0 += v.x; q0 += (double)v.x * v.x;
    s1 += v.y; q1 += (double)v.y * v.y;
    s2 += v.z; q2 += (double)v.z * v.z;
    s3 += v.w; q3 += (double)v.w * v.w;
  }
  double* ps = psum + (size_t)b * D_ + 4 * tid;
  double* pq = psq  + (size_t)b * D_ + 4 * tid;
  ps[0]=s0; ps[1]=s1; ps[2]=s2; ps[3]=s3;
  pq[0]=q0; pq[1]=q1; pq[2]=q2; pq[3]=q3;
}

// ---------------- stats phase B: reduce partials -> c = mean/sqrt(var+eps) ----------------
__global__ void stats_red(const double* __restrict__ psum, const double* __restrict__ psq,
                          float* __restrict__ cX, float* __restrict__ cY) {
  int g = blockIdx.x * 64 + threadIdx.x;   // 2048 threads: matrix = g>>10, col = g&1023
  int m = g >> 10, col = g & 1023;
  const double* ps = psum + (size_t)m * SB * D_ + col;
  const double* pq = psq  + (size_t)m * SB * D_ + col;
  double S = 0.0, Q = 0.0;
  for (int p2 = 0; p2 < SB; ++p2) { S += ps[(size_t)p2 * D_]; Q += pq[(size_t)p2 * D_]; }
  double mean = S / (double)N_;
  double var  = (Q - S * S / (double)N_) / (double)(N_ - 1);
  (m ? cY : cX)[col] = (float)(mean / sqrt(var + 1e-4));
}

// ---------------- normalize rows + row sum-of-squares ----------------
__global__ void norm_kernel(const float* __restrict__ X, const float* __restrict__ Y,
                            const float* __restrict__ cX, const float* __restrict__ cY,
                            float* __restrict__ Xn, float* __restrict__ Yn,
                            float* __restrict__ xsq, float* __restrict__ ysq) {
  int b = blockIdx.x;
  bool isY = b >= N_;
  int i = isY ? b - N_ : b;
  const float* src = isY ? Y : X;
  const float* c   = isY ? cY : cX;
  float* dst = isY ? Yn : Xn;
  float* rs  = isY ? ysq : xsq;
  int tid = threadIdx.x;                     // 256
  const float4 x  = reinterpret_cast<const float4*>(src + (size_t)i * D_)[tid];
  const float4 cc = reinterpret_cast<const float4*>(c)[tid];
  float4 o = make_float4(x.x - cc.x, x.y - cc.y, x.z - cc.z, x.w - cc.w);
  reinterpret_cast<float4*>(dst + (size_t)i * D_)[tid] = o;
  float ss = o.x*o.x + o.y*o.y + o.z*o.z + o.w*o.w;
  for (int off = 32; off; off >>= 1) ss += __shfl_xor(ss, off);
  __shared__ float wsum[4];
  if ((tid & 63) == 0) wsum[tid >> 6] = ss;
  __syncthreads();
  if (tid == 0) rs[i] = (wsum[0] + wsum[1]) + (wsum[2] + wsum[3]);
}

// ---------------- build banded k (f64), k^T band, and banded d (f32) ----------------
__global__ void band_kernel(const float* __restrict__ Xn, const float* __restrict__ Yn,
                            const float* __restrict__ xsq, const float* __restrict__ ysq,
                            double* __restrict__ kband, double* __restrict__ ktband,
                            float* __restrict__ dband) {
  int i = blockIdx.x;
  int tid = threadIdx.x;                 // 256
  int lane = tid & 63, wv = tid >> 6;
  __shared__ float Xs[D_];
  reinterpret_cast<float4*>(Xs)[tid] = reinterpret_cast<const float4*>(Xn + (size_t)i * D_)[tid];
  for (int dp = tid; dp < BW; dp += 256) {
    int isrc = i - BHW + dp;
    if (isrc < 0 || isrc >= N_) ktband[(size_t)i * WPAD + dp] = 0.0;
  }
  __syncthreads();
  float4 xf[4];
  #pragma unroll
  for (int q = 0; q < 4; ++q) xf[q] = reinterpret_cast<const float4*>(Xs)[q * 64 + lane];
  float xsqi = xsq[i];
  for (int dd = wv; dd < BW; dd += 4) {
    int j = i - BHW + dd;
    if (j < 0 || j >= M_) {
      if (lane == 0) { kband[(size_t)i*WPAD+dd] = 0.0; dband[(size_t)i*WPAD+dd] = 0.0f; }
      continue;
    }
    const float4* yr = reinterpret_cast<const float4*>(Yn + (size_t)j * D_);
    float acc = 0.0f;
    #pragma unroll
    for (int q = 0; q < 4; ++q) {
      float4 y = yr[q * 64 + lane];
      acc = fmaf(xf[q].x, y.x, acc);
      acc = fmaf(xf[q].y, y.y, acc);
      acc = fmaf(xf[q].z, y.z, acc);
      acc = fmaf(xf[q].w, y.w, acc);
    }
    for (int off = 32; off; off >>= 1) acc += __shfl_xor(acc, off);
    if (lane == 0) {
      float dv = xsqi + ysq[j] - 2.0f * acc;
      double diff = (double)(i - j) / 2048.0;
      double mid  = sqrt(1.0/((double)N_*(double)N_) + 1.0/((double)M_*(double)M_));
      double dpos = fabs(diff) / mid;
      double p = exp(-(dpos * dpos) / 2.0) / 2.5066282746310002;
      double s = 50.0 / (diff * diff + 1.0);
      double kk = p * exp((s - (double)dv) / 0.1);
      kband[(size_t)i * WPAD + dd] = kk;
      dband[(size_t)i * WPAD + dd] = dv;
      ktband[(size_t)j * WPAD + (2 * BHW - dd)] = kk;
    }
  }
}

// ------- epoch flag-array grid barrier: RELAXED polls, ONE release/acquire fence -------
// Agent-scope ACQUIRE loads emit buffer_inv (full L2 invalidate) PER POLL on gfx950 —
// that was ~13us/barrier in rounds 3/6. Relaxed agent atomics still bypass to the
// coherent point (sc0/sc1) without the cache maintenance; we fence once per side.
// Safety valve: if a poll somehow spins >4096 sleeps (~0.1ms; never in normal runs),
// issue an acquire fence inside the loop — converts any stale-line hang into a slow path.
__device__ __forceinline__ void poll_ge(int* addr, int ep) {
  int spins = 0;
  while (__hip_atomic_load(addr, __ATOMIC_RELAXED, __HIP_MEMORY_SCOPE_AGENT) < ep) {
    __builtin_amdgcn_s_sleep(1);
    if (++spins >= 4096) {
      spins = 0;
      __builtin_amdgcn_fence(__ATOMIC_ACQUIRE, "agent");
    }
  }
}

__device__ __forceinline__ void gbar(int* flags, int* go, int ep) {
  __syncthreads();
  if (blockIdx.x == 0) {
    int t = threadIdx.x;
    if (t >= 1 && t < NB) poll_ge(&flags[t * 16], ep);
    __syncthreads();
    if (t == 0) {
      // release our writes + acquire everyone's (single wbl2 + inv for the block)
      __builtin_amdgcn_fence(__ATOMIC_ACQ_REL, "agent");
      __hip_atomic_store(go, ep, __ATOMIC_RELAXED, __HIP_MEMORY_SCOPE_AGENT);
    }
  } else {
    if (threadIdx.x == 0) {
      __builtin_amdgcn_fence(__ATOMIC_RELEASE, "agent");   // flush this block's u writes
      __hip_atomic_store(&flags[blockIdx.x * 16], ep, __ATOMIC_RELAXED, __HIP_MEMORY_SCOPE_AGENT);
      poll_ge(go, ep);
      __builtin_amdgcn_fence(__ATOMIC_ACQUIRE, "agent");   // see other blocks' u writes
    }
  }
  __syncthreads();
}

// ---------------- persistent fused Sinkhorn + crit + dis + t ----------------
// 128 blocks x 256 threads. k rows live in REGISTERS (iteration-invariant);
// u halo staged in LDS each seg; one grid barrier per seg.
// crit/dis: each block reduces ONLY its own 16 rows (128*16 = 2048, no overlap).
__global__ void __launch_bounds__(256, 1)
sink_kernel(const double* __restrict__ kband, const double* __restrict__ ktband,
            const float* __restrict__ dband,
            double* __restrict__ uA, double* __restrict__ uB, double* __restrict__ vfin,
            double* __restrict__ critacc, double* __restrict__ disacc,
            int* flags, int* go, float* __restrict__ out) {
  const int tid = threadIdx.x;
  const int i0 = blockIdx.x * ROWS;
  const int gtid = blockIdx.x * 256 + tid;
  const int p = tid & 3, o0 = tid >> 2;     // 64 dot-groups x 4 d-quarter lanes

  __shared__ double ush[240];               // u halo [i0-108, i0+124) + zero pad
  __shared__ double vsh[128];               // v halo [i0-54, i0+70) + zero pad

  // init u buffers (incl. zero pads) and accumulators
  for (int q = gtid; q < UN; q += NB * 256) {
    int idx = q - UHALO;
    uA[q] = (idx >= 0 && idx < N_) ? (1.0 / (double)N_) : 0.0;
    uB[q] = 0.0;
    vfin[q] = 0.0;
  }
  if (gtid == 0) { *critacc = 0.0; *disacc = 0.0; }
  if (tid >= VW && tid < 128) vsh[tid] = 0.0;   // zero vsh pad once (never rewritten)

  // hoist iteration-invariant k rows into registers (static indices -> VGPRs)
  double kv1[28], kv2[28], ku[28];
  {
    int j1 = i0 - BHW + o0;          // v-round-1 row
    bool ok1 = (j1 >= 0 && j1 < M_);
    int j2 = j1 + 64;                // v-round-2 row
    bool ok2 = (o0 < VW - 64) && (j2 < M_);
    int iu = i0 + o0;                // u-phase row (only o0<ROWS used)
    bool oku = (o0 < ROWS);
    #pragma unroll
    for (int d2 = 0; d2 < 28; ++d2) {
      int dd = p * 28 + d2;
      bool din = dd < BW;            // skip the 3 poisoned pad slots
      kv1[d2] = (ok1 && din) ? ktband[(size_t)j1 * WPAD + dd] : 0.0;
      kv2[d2] = (ok2 && din) ? ktband[(size_t)j2 * WPAD + dd] : 0.0;
      ku[d2]  = (oku && din) ? kband[(size_t)iu * WPAD + dd] : 0.0;
    }
  }

  int ep = 0;
  double* cur = uA; double* nxt = uB;

  auto seg = [&](int writeV) {
    ++ep; gbar(flags, go, ep);                 // prev u writes visible
    for (int q = tid; q < 240; q += 256)
      ush[q] = (q < USHW) ? cur[UHALO + i0 - 2 * BHW + q] : 0.0;
    __syncthreads();
    // v-phase round 1: v_j, j = i0-54+o0
    double w = 0.0;
    #pragma unroll
    for (int d2 = 0; d2 < 28; ++d2) w += kv1[d2] * ush[o0 + p * 28 + d2];
    w += __shfl_xor(w, 1); w += __shfl_xor(w, 2);
    if (p == 0) {
      int j = i0 - BHW + o0;
      vsh[o0] = (j >= 0 && j < M_) ? (1.0 / (double)M_) / w : 0.0;
    }
    // v-phase round 2: j = i0-54+o0+64
    double w2 = 0.0;
    #pragma unroll
    for (int d2 = 0; d2 < 28; ++d2) w2 += kv2[d2] * ush[o0 + 64 + p * 28 + d2];
    w2 += __shfl_xor(w2, 1); w2 += __shfl_xor(w2, 2);
    if (p == 0 && o0 < VW - 64) {
      int j = i0 - BHW + o0 + 64;
      vsh[o0 + 64] = (j < M_) ? (1.0 / (double)M_) / w2 : 0.0;
    }
    __syncthreads();
    // u-phase: u_i, i = i0+o0 (o0 < 16)
    if (o0 < ROWS) {
      double acc = 0.0;
      #pragma unroll
      for (int d2 = 0; d2 < 28; ++d2) acc += ku[d2] * vsh[o0 + p * 28 + d2];
      acc += __shfl_xor(acc, 1); acc += __shfl_xor(acc, 2);
      if (p == 0) {
        nxt[UHALO + i0 + o0] = 1.0 / ((double)N_ * acc);  // ainvK = k*n (exact 2^11 scale)
        if (writeV) vfin[UHALO + i0 + o0] = vsh[o0 + BHW];
      }
    }
    double* t = cur; cur = nxt; nxt = t;
  };

  seg(0);            // u1 (plain update #1)
  seg(1);            // v1 = b/(K^T u1); u2 = 1/(ainvK v1)
  ++ep; gbar(flags, go, ep);   // u2, vfin visible

  // crit = sum |v1 * (K^T u2) - b| : this block's 16 rows only
  if (tid < 64) {
    int j = i0 + (tid >> 2);           // 16 rows x 4 quarter-lanes
    const double* kr = ktband + (size_t)j * WPAD + p * 28;
    const double* u  = cur + UHALO + j - BHW + p * 28;
    int dc = (p == 3) ? 25 : 28;
    double w = 0.0;
    for (int d2 = 0; d2 < dc; ++d2) w += kr[d2] * u[d2];
    w += __shfl_xor(w, 1); w += __shfl_xor(w, 2);
    double c = (p == 0) ? fabs(vfin[UHALO + j] * w - 1.0 / (double)M_) : 0.0;
    for (int off = 4; off <= 32; off <<= 1) c += __shfl_xor(c, off);
    if (tid == 0) atomicAdd(critacc, c);
  }
  ++ep; gbar(flags, go, ep);   // critacc complete

  double cv = *critacc;
  bool done = (cv < 0.005) || isnan(cv);   // uniform across grid
  if (!done) {
    for (int it = 0; it < 18; ++it) seg(0);
    seg(1);
  }
  ++ep; gbar(flags, go, ep);   // final u/v visible

  // dis = sum(u * ((k .* d) @ v)) : this block's 16 rows only
  if (tid < 64) {
    int i = i0 + (tid >> 2);
    const double* kr = kband + (size_t)i * WPAD + p * 28;
    const float*  dr = dband + (size_t)i * WPAD + p * 28;
    const double* vr = vfin + UHALO + i - BHW + p * 28;
    int dc = (p == 3) ? 25 : 28;
    double acc = 0.0;
    for (int d2 = 0; d2 < dc; ++d2) acc += kr[d2] * (double)dr[d2] * vr[d2];
    acc += __shfl_xor(acc, 1); acc += __shfl_xor(acc, 2);
    double c = (p == 0) ? acc * cur[UHALO + i] : 0.0;
    for (int off = 4; off <= 32; off <<= 1) c += __shfl_xor(c, off);
    if (tid == 0) atomicAdd(disacc, c);
  }
  ++ep; gbar(flags, go, ep);   // disacc complete

  // out[0] = dis ; out[1..] = t = v^T * (u .* k), zero outside band
  if (gtid == 0) out[0] = (float)(*disacc);
  for (int idx = gtid; idx < N_ * M_; idx += NB * 256) {
    int i = idx >> 11, j = idx & 2047;
    int dd = j - i + BHW;
    float tv = 0.0f;
    if (dd >= 0 && dd < BW)
      tv = (float)(cur[UHALO + i] * kband[(size_t)i * WPAD + dd] * vfin[UHALO + j]);
    out[1 + idx] = tv;
  }
}

extern "C" void kernel_launch(void* const* d_in, const int* in_sizes, int n_in,
                              void* d_out, int out_size, void* d_ws, size_t ws_size,
                              hipStream_t stream) {
  const float* X = (const float*)d_in[0];
  const float* Y = (const float*)d_in[1];
  float* out = (float*)d_out;

  char* pp = (char*)d_ws;
  auto alloc = [&](size_t bytes) -> char* {
    char* r = pp; pp += (bytes + 255) & ~(size_t)255; return r;
  };
  float*  Xn     = (float*) alloc(sizeof(float)  * (size_t)N_ * D_);
  float*  Yn     = (float*) alloc(sizeof(float)  * (size_t)M_ * D_);
  float*  cX     = (float*) alloc(sizeof(float)  * D_);
  float*  cY     = (float*) alloc(sizeof(float)  * D_);
  float*  xsq    = (float*) alloc(sizeof(float)  * N_);
  float*  ysq    = (float*) alloc(sizeof(float)  * M_);
  float*  dband  = (float*) alloc(sizeof(float)  * (size_t)N_ * WPAD);
  double* kband  = (double*)alloc(sizeof(double) * (size_t)N_ * WPAD);
  double* ktband = (double*)alloc(sizeof(double) * (size_t)M_ * WPAD);
  double* psum   = (double*)alloc(sizeof(double) * (size_t)2 * SB * D_);
  double* psq    = (double*)alloc(sizeof(double) * (size_t)2 * SB * D_);
  double* uA     = (double*)alloc(sizeof(double) * UN);
  double* uB     = (double*)alloc(sizeof(double) * UN);
  double* vfin   = (double*)alloc(sizeof(double) * UN);
  double* critacc= (double*)alloc(256);
  double* disacc = (double*)alloc(256);
  int*    flags  = (int*)   alloc(sizeof(int) * NB * 16);
  int*    go     = (int*)   alloc(256);

  stats_part<<<2 * SB, 256, 0, stream>>>(X, Y, psum, psq);
  stats_red<<<32, 64, 0, stream>>>(psum, psq, cX, cY);
  norm_kernel<<<2 * N_, 256, 0, stream>>>(X, Y, cX, cY, Xn, Yn, xsq, ysq);
  band_kernel<<<N_, 256, 0, stream>>>(Xn, Yn, xsq, ysq, kband, ktband, dband);
  sink_kernel<<<NB, 256, 0, stream>>>(kband, ktband, dband, uA, uB, vfin,
                                      critacc, disacc, flags, go, out);
}